// Round 10
// baseline (632.516 us; speedup 1.0000x reference)
//
#include <hip/hip_runtime.h>
#include <math.h>

// Problem constants (from reference)
#define NWAY   10
#define DIMD   64
#define HWN    49           // H*W = 7*7
#define NSUP   800          // N_WAY*K_SHOT*PRJ
#define NQRY   16000        // N_WAY*Q_QUERY*PRJ
#define NTRI   2080         // 64*65/2
#define FEAT_PER (DIMD*HWN) // 3136 floats per sample

typedef __attribute__((ext_vector_type(8))) short bf16x8;
typedef __attribute__((ext_vector_type(4))) float f32x4;

// ---- single-query shared block (kern_support) -------------------------------
struct __align__(16) BDCShared {
    union {
        unsigned short hl[2*DIMD*64];    // 16384 B: H[64][64], L[64][64]
        float dcov[DIMD*64];             // 16384 B: CENTERED dcov, swizzled
    } u;
    float dg[DIMD];
    float rm[DIMD];
    float w4[4];
};

// Map linear triu index k -> (i,j), j>=i, row-major triu of 64x64 (init only).
__device__ __forceinline__ void k2ij(int k, int& io, int& jo) {
    int ii = (int)floorf((129.0f - sqrtf(16641.0f - 8.0f*(float)k)) * 0.5f);
    int off = ii*(129-ii)/2;
    if (off > k) { --ii; off = ii*(129-ii)/2; }
    else {
        int off2 = (ii+1)*(128-ii)/2;
        if (off2 <= k) { ii += 1; off = off2; }
    }
    io = ii;
    jo = ii + (k - off);
}

// HW packed bf16 convert (RNE): r.lo16 = bf16(a), r.hi16 = bf16(b)
__device__ __forceinline__ unsigned cvt_pk_bf16(float a, float b) {
    unsigned r;
    asm("v_cvt_pk_bf16_f32 %0, %1, %2" : "=v"(r) : "v"(a), "v"(b));
    return r;
}

// 8 floats -> H/L bf16x8 split (H = bf16(x), L = bf16(x - H))
__device__ __forceinline__ void pack_hl(const float* x, bf16x8& H, bf16x8& L) {
    unsigned hh[4], ll[4];
    #pragma unroll
    for (int p = 0; p < 4; ++p) {
        unsigned h = cvt_pk_bf16(x[2*p], x[2*p+1]);
        float f0 = __uint_as_float(h << 16);
        float f1 = __uint_as_float(h & 0xffff0000u);
        hh[p] = h;
        ll[p] = cvt_pk_bf16(x[2*p] - f0, x[2*p+1] - f1);
    }
    union { uint4 u; bf16x8 b; } cu;
    cu.u = make_uint4(hh[0], hh[1], hh[2], hh[3]); H = cu.b;
    cu.u = make_uint4(ll[0], ll[1], ll[2], ll[3]); L = cu.b;
}

// bf16 staging: row-major [64][64] shorts, swizzled in 8-short (16B) chunks.
#define HL_ADDR(BASE, row, e) \
    ((BASE) + (row)*64 + (((((e) >> 3) ^ ((row) & 7))) << 3))

// ============================================================================
// Single-query cooperative BDC (kern_support only; unchanged, known-good).
// ============================================================================
__device__ __forceinline__ float bdc_compute(const float* __restrict__ feat,
                                             float et, int sample, BDCShared& sm,
                                             f32x4& v0, f32x4& v1, f32x4& v2,
                                             f32x4& v3) {
    const int tid = threadIdx.x;
    unsigned short* Hh = sm.u.hl;
    unsigned short* Lh = sm.u.hl + DIMD*64;
    {
        const int d = tid & 63, hq = tid >> 6;
        const float* rowp = feat + (size_t)sample * FEAT_PER + d*HWN + hq*16;
        float x[16];
        if (hq < 3) {
            #pragma unroll
            for (int i = 0; i < 16; ++i) x[i] = rowp[i];
        } else {
            x[0] = rowp[0];
            #pragma unroll
            for (int i = 1; i < 16; ++i) x[i] = 0.0f;
        }
        bf16x8 hA, lA, hB, lB;
        pack_hl(x, hA, lA);
        pack_hl(x + 8, hB, lB);
        const int sw0 = (hq*2) ^ (d & 7);
        const int sw1 = (hq*2 + 1) ^ (d & 7);
        *(bf16x8*)&Hh[d*64 + sw0*8] = hA;
        *(bf16x8*)&Hh[d*64 + sw1*8] = hB;
        *(bf16x8*)&Lh[d*64 + sw0*8] = lA;
        *(bf16x8*)&Lh[d*64 + sw1*8] = lB;
    }
    __syncthreads();

    const int wv = tid >> 6, lane = tid & 63;
    const int qd = lane >> 4, c15 = lane & 15;
    const int rA = 16*wv + c15;
    bf16x8 AH0 = *(const bf16x8*)HL_ADDR(Hh, rA, qd*8);
    bf16x8 AH1 = *(const bf16x8*)HL_ADDR(Hh, rA, qd*8 + 32);
    bf16x8 AL0 = *(const bf16x8*)HL_ADDR(Lh, rA, qd*8);
    bf16x8 AL1 = *(const bf16x8*)HL_ADDR(Lh, rA, qd*8 + 32);

    f32x4 acc[4];
    #pragma unroll
    for (int J = 0; J < 4; ++J) {
        const int rB = 16*J + c15;
        bf16x8 BH0 = *(const bf16x8*)HL_ADDR(Hh, rB, qd*8);
        bf16x8 BH1 = *(const bf16x8*)HL_ADDR(Hh, rB, qd*8 + 32);
        bf16x8 BL0 = *(const bf16x8*)HL_ADDR(Lh, rB, qd*8);
        bf16x8 BL1 = *(const bf16x8*)HL_ADDR(Lh, rB, qd*8 + 32);
        f32x4 a = {0.f, 0.f, 0.f, 0.f};
        a = __builtin_amdgcn_mfma_f32_16x16x32_bf16(AH0, BH0, a, 0, 0, 0);
        a = __builtin_amdgcn_mfma_f32_16x16x32_bf16(AH1, BH1, a, 0, 0, 0);
        a = __builtin_amdgcn_mfma_f32_16x16x32_bf16(AL0, BH0, a, 0, 0, 0);
        a = __builtin_amdgcn_mfma_f32_16x16x32_bf16(AL1, BH1, a, 0, 0, 0);
        a = __builtin_amdgcn_mfma_f32_16x16x32_bf16(AH0, BL0, a, 0, 0, 0);
        a = __builtin_amdgcn_mfma_f32_16x16x32_bf16(AH1, BL1, a, 0, 0, 0);
        acc[J] = a;
    }

    #pragma unroll
    for (int J = 0; J < 4; ++J) {
        if (J == wv) {
            #pragma unroll
            for (int r = 0; r < 4; ++r)
                if (c15 == 4*qd + r) sm.dg[16*wv + c15] = acc[J][r];
        }
    }
    __syncthreads();

    f32x4 dgi = *(const f32x4*)&sm.dg[16*wv + 4*qd];
    float rs0 = 0.f, rs1 = 0.f, rs2 = 0.f, rs3 = 0.f;
#define DCOV_J(J, VJ)                                                          \
    {   float dgj = sm.dg[16*(J) + c15];                                       \
        _Pragma("unroll")                                                      \
        for (int r = 0; r < 4; ++r) {                                          \
            float t2 = fmaf(-2.0f, acc[J][r], dgi[r] + dgj);                   \
            t2 = fmaxf(t2, 0.0f);                                              \
            VJ[r] = __builtin_amdgcn_sqrtf(fmaf(et, t2, 1e-5f));               \
        }                                                                      \
        rs0 += VJ[0]; rs1 += VJ[1]; rs2 += VJ[2]; rs3 += VJ[3]; }
    DCOV_J(0, v0)
    DCOV_J(1, v1)
    DCOV_J(2, v2)
    DCOV_J(3, v3)
#undef DCOV_J

    #pragma unroll
    for (int off = 1; off < 16; off <<= 1) {
        rs0 += __shfl_xor(rs0, off, 64);
        rs1 += __shfl_xor(rs1, off, 64);
        rs2 += __shfl_xor(rs2, off, 64);
        rs3 += __shfl_xor(rs3, off, 64);
    }
    if (c15 == 0) {
        f32x4 rmv = {rs0*(1.0f/64.0f), rs1*(1.0f/64.0f),
                     rs2*(1.0f/64.0f), rs3*(1.0f/64.0f)};
        *(f32x4*)&sm.rm[16*wv + 4*qd] = rmv;
    }
    float tt = (rs0 + rs1) + (rs2 + rs3);
    tt += __shfl_xor(tt, 16, 64);
    tt += __shfl_xor(tt, 32, 64);
    if (lane == 0) sm.w4[wv] = tt;
    __syncthreads();
    float tm = (sm.w4[0] + sm.w4[1] + sm.w4[2] + sm.w4[3]) * (1.0f/4096.0f);

    const float rmi0 = rs0*(1.0f/64.0f), rmi1 = rs1*(1.0f/64.0f),
                rmi2 = rs2*(1.0f/64.0f), rmi3 = rs3*(1.0f/64.0f);
#define CENTER_J(J, VJ)                                                        \
    {   float rmj = sm.rm[16*(J) + c15] - tm;                                  \
        VJ[0] = VJ[0] - rmi0 - rmj;                                            \
        VJ[1] = VJ[1] - rmi1 - rmj;                                            \
        VJ[2] = VJ[2] - rmi2 - rmj;                                            \
        VJ[3] = VJ[3] - rmi3 - rmj; }
    CENTER_J(0, v0)
    CENTER_J(1, v1)
    CENTER_J(2, v2)
    CENTER_J(3, v3)
#undef CENTER_J
    return tm;
}

// ============================================================================
// Support: BDC -> centered triu vector scattered from registers.
// FUSED init: blocks 0..8 build the (i<<8|j) table and zero s2/loss.
// ============================================================================
__global__ __launch_bounds__(256, 8) void kern_support(const float* __restrict__ feat,
                                                       const float* __restrict__ temp,
                                                       float* __restrict__ tvout,
                                                       unsigned* __restrict__ table,
                                                       float* __restrict__ s2,
                                                       float* __restrict__ loss_slot) {
    const int tid = threadIdx.x;
    if (blockIdx.x < 9) {
        int i = blockIdx.x * 256 + tid;
        if (i < NTRI) {
            int ii, jj; k2ij(i, ii, jj);
            table[i] = ((unsigned)ii << 8) | (unsigned)jj;
        }
        if (i < NWAY) s2[i] = 0.0f;
        if (i == 0) loss_slot[0] = 0.0f;
    }

    __shared__ BDCShared sm;
    float et = __expf(temp[0]);
    int s = blockIdx.x;                 // 0..799
    f32x4 v0, v1, v2, v3;
    bdc_compute(feat, et, s, sm, v0, v1, v2, v3);

    const int wv = tid >> 6, lane = tid & 63;
    const int qd = lane >> 4, c15 = lane & 15;
    const int iB = 16*wv + 4*qd;
    float* dst = tvout + (size_t)s * NTRI;
#define SUP_J(J, VJ)                                                           \
    {   int j = 16*(J) + c15;                                                  \
        _Pragma("unroll")                                                      \
        for (int r = 0; r < 4; ++r) {                                          \
            int i = iB + r;                                                    \
            if (j >= i) dst[i*(129 - i)/2 + (j - i)] = VJ[r]; } }
    SUP_J(0, v0)
    SUP_J(1, v1)
    SUP_J(2, v2)
    SUP_J(3, v3)
#undef SUP_J
}

// ============================================================================
// Reduce: prototype means -> FULL symmetric Sfull[m][64][64] + s2 (r2 form).
// Grid = NWAY * 9 blocks.
// ============================================================================
__global__ __launch_bounds__(256) void kern_reduce(const float* __restrict__ tv,
                                                   const unsigned* __restrict__ table,
                                                   float* __restrict__ Sfull,
                                                   float* __restrict__ s2) {
    __shared__ float red[4];
    int m = blockIdx.x / 9, kc = blockIdx.x % 9;
    int k = kc*256 + threadIdx.x;
    float ps = 0.0f;
    if (k < NTRI) {
        const float* p = tv + (size_t)(80*m) * NTRI + k;
        float a0 = 0.f, a1 = 0.f, a2 = 0.f, a3 = 0.f;
        for (int s4 = 0; s4 < 80; s4 += 4) {
            a0 += p[(size_t)(s4+0)*NTRI];
            a1 += p[(size_t)(s4+1)*NTRI];
            a2 += p[(size_t)(s4+2)*NTRI];
            a3 += p[(size_t)(s4+3)*NTRI];
        }
        float S = ((a0+a1)+(a2+a3)) * (1.0f/80.0f);
        unsigned t = table[k];
        int ii = (int)((t >> 8) & 255u), jj = (int)(t & 255u);
        float* Sm = Sfull + (size_t)m * 4096;
        Sm[ii*64 + jj] = S;
        Sm[jj*64 + ii] = S;
        ps = S * S;
    }
    int lane = threadIdx.x & 63, wv = threadIdx.x >> 6;
    #pragma unroll
    for (int off = 32; off > 0; off >>= 1) ps += __shfl_xor(ps, off, 64);
    if (lane == 0) red[wv] = ps;
    __syncthreads();
    if (threadIdx.x == 0) atomicAdd(&s2[m], red[0]+red[1]+red[2]+red[3]);
}

// ============================================================================
// Query: ONE WAVE PER QUERY, 4 queries/block, ZERO __syncthreads.
// Lane loads rows 16J+c15 global->reg, builds all 16 H/L frags, computes all
// 16 MFMA tiles (A=frag[I], B=frag[J] -- identical operand layout, proven by
// the support path). dcov/center/score stay in registers; LDS = 544 B/wave
// (dg+rm, same-wave lgkmcnt fences only). Tail: full-matrix half-weight dot
// against Sfull (validated r2):  u = 0.5*v (diag restored to v),
// cross_triu = sum_full u*S ;  qq_triu = 2*sum u^2 - sum_diag u^2.
// Fused softmax-NLL: one atomicAdd per wave.
// ============================================================================
__global__ __launch_bounds__(256, 3) void kern_query(const float* __restrict__ feat,
                                                     const float* __restrict__ temp,
                                                     const float* __restrict__ Sfull,
                                                     const float* __restrict__ s2,
                                                     const int* __restrict__ label,
                                                     float* __restrict__ out,
                                                     float* __restrict__ loss_out) {
    __shared__ float dgrm[4][136];     // per wave: [0..63]=dg, [64..127]=rm
    const int tid = threadIdx.x;
    const int w = tid >> 6, lane = tid & 63;
    const int qd = lane >> 4, c15 = lane & 15;
    const float et = __expf(temp[0]);
    const int qn = blockIdx.x * 4 + w;
    const float* fp = feat + (size_t)(NSUP + qn) * FEAT_PER;

    // ---- global -> register frags: rows 16J+c15, k in [8qd,8qd+8) & [32+8qd,..)
    bf16x8 fH0[4], fH1[4], fL0[4], fL1[4];
    #pragma unroll
    for (int J = 0; J < 4; ++J) {
        const float* rp = fp + (16*J + c15)*HWN;
        float xa[8], xb[8];
        #pragma unroll
        for (int t = 0; t < 8; ++t) {
            xa[t] = rp[qd*8 + t];                    // k <= 31 < 49: valid
            int k = 32 + qd*8 + t;
            xb[t] = (k < HWN) ? rp[k] : 0.0f;        // predicated: OOB-safe
        }
        pack_hl(xa, fH0[J], fL0[J]);
        pack_hl(xb, fH1[J], fL1[J]);
    }

    // ---- Gram: all 16 tiles. C layout per tile: row=16I+4qd+r, col=16J+c15.
    f32x4 acc[4][4];
    #pragma unroll
    for (int I = 0; I < 4; ++I) {
        #pragma unroll
        for (int J = 0; J < 4; ++J) {
            f32x4 a = {0.f, 0.f, 0.f, 0.f};
            a = __builtin_amdgcn_mfma_f32_16x16x32_bf16(fH0[I], fH0[J], a, 0, 0, 0);
            a = __builtin_amdgcn_mfma_f32_16x16x32_bf16(fH1[I], fH1[J], a, 0, 0, 0);
            a = __builtin_amdgcn_mfma_f32_16x16x32_bf16(fL0[I], fH0[J], a, 0, 0, 0);
            a = __builtin_amdgcn_mfma_f32_16x16x32_bf16(fL1[I], fH1[J], a, 0, 0, 0);
            a = __builtin_amdgcn_mfma_f32_16x16x32_bf16(fH0[I], fL0[J], a, 0, 0, 0);
            a = __builtin_amdgcn_mfma_f32_16x16x32_bf16(fH1[I], fL1[J], a, 0, 0, 0);
            acc[I][J] = a;
        }
    }

    // ---- dg via per-wave LDS (no barrier: same-wave lgkmcnt ordering)
    #pragma unroll
    for (int I = 0; I < 4; ++I) {
        #pragma unroll
        for (int r = 0; r < 4; ++r)
            if (c15 == 4*qd + r) dgrm[w][16*I + c15] = acc[I][I][r];
    }
    asm volatile("s_waitcnt lgkmcnt(0)" ::: "memory");
    f32x4 dgi[4];
    float dgj[4];
    #pragma unroll
    for (int I = 0; I < 4; ++I) dgi[I] = *(const f32x4*)&dgrm[w][16*I + 4*qd];
    #pragma unroll
    for (int J = 0; J < 4; ++J) dgj[J] = dgrm[w][16*J + c15];

    // ---- dcov (sqrt'd, uncentered) + per-(I,r) row sums
    f32x4 vt[4][4];
    float rsum[4][4];
    #pragma unroll
    for (int I = 0; I < 4; ++I) {
        #pragma unroll
        for (int r = 0; r < 4; ++r) rsum[I][r] = 0.0f;
    }
    #pragma unroll
    for (int I = 0; I < 4; ++I) {
        #pragma unroll
        for (int J = 0; J < 4; ++J) {
            #pragma unroll
            for (int r = 0; r < 4; ++r) {
                float t2 = fmaf(-2.0f, acc[I][J][r], dgi[I][r] + dgj[J]);
                t2 = fmaxf(t2, 0.0f);
                float sv = __builtin_amdgcn_sqrtf(fmaf(et, t2, 1e-5f));
                vt[I][J][r] = sv;
                rsum[I][r] += sv;
            }
        }
    }
    // row sums complete across the 16 c15 lanes
    #pragma unroll
    for (int off = 1; off < 16; off <<= 1) {
        #pragma unroll
        for (int I = 0; I < 4; ++I) {
            #pragma unroll
            for (int r = 0; r < 4; ++r)
                rsum[I][r] += __shfl_xor(rsum[I][r], off, 64);
        }
    }
    // grand total -> tm
    float tot = 0.0f;
    #pragma unroll
    for (int I = 0; I < 4; ++I) {
        #pragma unroll
        for (int r = 0; r < 4; ++r) tot += rsum[I][r];
    }
    tot += __shfl_xor(tot, 16, 64);
    tot += __shfl_xor(tot, 32, 64);
    const float tm = tot * (1.0f/4096.0f);
    const float inv64 = 1.0f/64.0f;

    // publish rm (c15==0 lanes cover rows 16I+4qd+0..3 for all I)
    if (c15 == 0) {
        #pragma unroll
        for (int I = 0; I < 4; ++I) {
            f32x4 rmv = {rsum[I][0]*inv64, rsum[I][1]*inv64,
                         rsum[I][2]*inv64, rsum[I][3]*inv64};
            *(f32x4*)&dgrm[w][64 + 16*I + 4*qd] = rmv;
        }
    }
    asm volatile("s_waitcnt lgkmcnt(0)" ::: "memory");
    float rmj[4];
    #pragma unroll
    for (int J = 0; J < 4; ++J) rmj[J] = dgrm[w][64 + 16*J + c15];

    // ---- center + half-weight (vt becomes u)
    #pragma unroll
    for (int I = 0; I < 4; ++I) {
        #pragma unroll
        for (int J = 0; J < 4; ++J) {
            #pragma unroll
            for (int r = 0; r < 4; ++r)
                vt[I][J][r] = 0.5f*(vt[I][J][r] - rsum[I][r]*inv64 - rmj[J] + tm);
        }
    }
    float dadj = 0.0f;
    #pragma unroll
    for (int I = 0; I < 4; ++I) {
        if (qd == (c15 >> 2)) {          // lane owns diag elems (16I+c15,16I+c15)
            #pragma unroll
            for (int r = 0; r < 4; ++r)
                if ((c15 & 3) == r) {
                    vt[I][I][r] *= 2.0f;             // restore full v on diag
                    dadj += vt[I][I][r]*vt[I][I][r];
                }
        }
    }
    float qq2 = 0.0f;
    #pragma unroll
    for (int I = 0; I < 4; ++I) {
        #pragma unroll
        for (int J = 0; J < 4; ++J) {
            #pragma unroll
            for (int r = 0; r < 4; ++r)
                qq2 = fmaf(vt[I][J][r], vt[I][J][r], qq2);
        }
    }
    float qq = 2.0f*qq2 - dadj;

    // ---- cross: full-matrix dot vs each prototype (Sfull symmetric, L2-hot)
    float cr[NWAY];
    #pragma unroll
    for (int m = 0; m < NWAY; ++m) cr[m] = 0.0f;
    #pragma unroll
    for (int J = 0; J < 4; ++J) {
        #pragma unroll
        for (int I = 0; I < 4; ++I) {
            const float* sp = Sfull + (16*J + c15)*64 + 16*I + 4*qd;
            #pragma unroll
            for (int m = 0; m < NWAY; ++m) {
                f32x4 sf = *(const f32x4*)(sp + m*4096);
                cr[m] = fmaf(vt[I][J][0], sf[0], cr[m]);
                cr[m] = fmaf(vt[I][J][1], sf[1], cr[m]);
                cr[m] = fmaf(vt[I][J][2], sf[2], cr[m]);
                cr[m] = fmaf(vt[I][J][3], sf[3], cr[m]);
            }
        }
    }

    // ---- full-wave butterfly: all lanes end with the 11 totals
    #pragma unroll
    for (int m = 0; m < NWAY; ++m) {
        float v = cr[m];
        #pragma unroll
        for (int off = 1; off < 64; off <<= 1) v += __shfl_xor(v, off, 64);
        cr[m] = v;
    }
    #pragma unroll
    for (int off = 1; off < 64; off <<= 1) qq += __shfl_xor(qq, off, 64);

    float s2r[NWAY];
    #pragma unroll
    for (int m = 0; m < NWAY; ++m) s2r[m] = s2[m];

    #pragma unroll
    for (int m = 0; m < NWAY; ++m)
        if (lane == m) out[(size_t)qn * NWAY + m] = -(qq + s2r[m] - 2.0f*cr[m]);

    // ---- fused NLL (one atomicAdd per wave)
    if (lane == 0) {
        int lb = label[qn];
        float mx = -1e30f, tsc = 0.0f;
        #pragma unroll
        for (int m = 0; m < NWAY; ++m) {
            float sc = -(qq + s2r[m] - 2.0f*cr[m]);
            mx = fmaxf(mx, sc);
            if (m == lb) tsc = sc;
        }
        float se = 0.0f;
        #pragma unroll
        for (int m = 0; m < NWAY; ++m) {
            float sc = -(qq + s2r[m] - 2.0f*cr[m]);
            se += __expf(sc - mx);
        }
        atomicAdd(loss_out, (mx + __logf(se) - tsc) * (1.0f / (float)NQRY));
    }
}

extern "C" void kernel_launch(void* const* d_in, const int* in_sizes, int n_in,
                              void* d_out, int out_size, void* d_ws, size_t ws_size,
                              hipStream_t stream) {
    (void)in_sizes; (void)n_in; (void)out_size; (void)ws_size;
    const float* feat = (const float*)d_in[0];
    const float* temp = (const float*)d_in[1];
    const int*   label = (const int*)d_in[2];
    float* out = (float*)d_out;

    // workspace layout (~6.9 MB):
    float*    tv    = (float*)d_ws;                  // 800*2080 f = 6.656 MB
    float*    Sfull = tv + (size_t)NSUP * NTRI;      // 10*4096 f = 163.84 KB
    float*    s2    = Sfull + (size_t)NWAY * 4096;   // 10 f (+pad)
    unsigned* table = (unsigned*)(s2 + 16);          // 2080 u32
    float* loss_slot = out + (size_t)NQRY * NWAY;

    kern_support<<<NSUP, 256, 0, stream>>>(feat, temp, tv, table, s2, loss_slot);
    kern_reduce<<<NWAY*9, 256, 0, stream>>>(tv, table, Sfull, s2);
    kern_query<<<NQRY/4, 256, 0, stream>>>(feat, temp, Sfull, s2, label, out, loss_slot);
}